// Round 9
// baseline (347.163 us; speedup 1.0000x reference)
//
#include <hip/hip_runtime.h>
#include <cmath>

#define NB 4
#define NH 16
#define SD 64
#define SEQ 1024
#define ILEN 128
#define HIDDIM 1024

#define N_HID (NB*SEQ*HIDDIM)     // 4194304
#define N_INS (NB*ILEN*HIDDIM)    // 524288
#define N_E_SRC (2047*SD)         // 131008
#define N_E   (2048*SD)           // 131072 (incl zero pad row)
#define N_W   (HIDDIM*HIDDIM)     // 1048576

typedef short bf8 __attribute__((ext_vector_type(8)));
typedef short bf4 __attribute__((ext_vector_type(4)));
typedef float f4  __attribute__((ext_vector_type(4)));

#define MFMA(a,b,c) __builtin_amdgcn_mfma_f32_16x16x32_bf16(a,b,c,0,0,0)

// static softmax shift (R8-verified): shift-invariant, logits O(1).
#define SHIFT 12.0f

__device__ __forceinline__ float bf2f(short s) {
    unsigned u = ((unsigned)(unsigned short)s) << 16;
    return __uint_as_float(u);
}
__device__ __forceinline__ short f2bf(float x) {          // RNE
    unsigned u = __float_as_uint(x);
    u = (u + 0x7FFFu + ((u >> 16) & 1u)) >> 16;
    return (short)u;
}

// ---------------------------------------------------------------------------
// Cast fp32 -> bf16: hidden, instruct, dist_emb (+1 zero pad row for E)
// ---------------------------------------------------------------------------
__global__ __launch_bounds__(256) void cast_flat(
    const float* __restrict__ hid, const float* __restrict__ ins,
    const float* __restrict__ E, short* __restrict__ ws)
{
    int i = (blockIdx.x * 256 + threadIdx.x) * 4;
    short* dhid = ws;
    short* dins = ws + N_HID;
    short* dE   = ws + N_HID + N_INS;
    if (i < N_HID) {
        float4 v = *(const float4*)&hid[i];
        bf4 o; o[0]=f2bf(v.x); o[1]=f2bf(v.y); o[2]=f2bf(v.z); o[3]=f2bf(v.w);
        *(bf4*)&dhid[i] = o;
    } else if (i < N_HID + N_INS) {
        int j = i - N_HID;
        float4 v = *(const float4*)&ins[j];
        bf4 o; o[0]=f2bf(v.x); o[1]=f2bf(v.y); o[2]=f2bf(v.z); o[3]=f2bf(v.w);
        *(bf4*)&dins[j] = o;
    } else {
        int j = i - N_HID - N_INS;
        if (j < N_E) {
            bf4 o;
            if (j < N_E_SRC) {
                float4 v = *(const float4*)&E[j];
                o[0]=f2bf(v.x); o[1]=f2bf(v.y); o[2]=f2bf(v.z); o[3]=f2bf(v.w);
            } else {
                o[0]=0; o[1]=0; o[2]=0; o[3]=0;
            }
            *(bf4*)&dE[j] = o;
        }
    }
}

// ---------------------------------------------------------------------------
// Cast + transpose W -> WT bf16 (WT[n][k] = W[k][n]); grid (16,16,3)
// ---------------------------------------------------------------------------
__global__ __launch_bounds__(256) void cast_wt(
    const float* __restrict__ Wq, const float* __restrict__ Wk,
    const float* __restrict__ Wv, short* __restrict__ dstbase)
{
    const float* W = (blockIdx.z==0) ? Wq : (blockIdx.z==1) ? Wk : Wv;
    short* dst = dstbase + (size_t)blockIdx.z * N_W;
    const int k0 = blockIdx.y*64, n0 = blockIdx.x*64;
    __shared__ float st[64][65];
    const int tid = threadIdx.x;
    #pragma unroll
    for (int rep=0; rep<4; rep++) {
        int u = tid + rep*256;
        int row = u >> 4, col = (u & 15) * 4;
        float4 v = *(const float4*)&W[(size_t)(k0+row)*HIDDIM + n0 + col];
        st[row][col+0]=v.x; st[row][col+1]=v.y; st[row][col+2]=v.z; st[row][col+3]=v.w;
    }
    __syncthreads();
    #pragma unroll
    for (int rep=0; rep<4; rep++) {
        int u = tid + rep*256;
        int nrow = u >> 4, kc = (u & 15) * 4;
        bf4 o;
        #pragma unroll
        for (int j=0;j<4;j++) o[j] = f2bf(st[kc+j][nrow]);
        *(bf4*)&dst[(size_t)(n0+nrow)*HIDDIM + k0 + kc] = o;
    }
}

// ---------------------------------------------------------------------------
// Fused projection GEMM (bf16 MFMA), 128x128 tiles, BK=64, 4 waves (2x2).
// Register-prefetch pipeline: next k-tile loaded into VGPRs during compute.
// ---------------------------------------------------------------------------
__global__ __launch_bounds__(256) void proj_mfma(
    const short* __restrict__ hidb, const short* __restrict__ insb,
    const short* __restrict__ WTall,
    const float* __restrict__ bq, const float* __restrict__ bk, const float* __restrict__ bv,
    short* __restrict__ qo, short* __restrict__ ko, short* __restrict__ vTo,
    short* __restrict__ iko, short* __restrict__ ivTo)
{
    const int z = blockIdx.z;
    const int bx = blockIdx.x, by = blockIdx.y;
    if (z==1 && (bx>=16 || by>=4)) return;
    const short* X = z ? insb : hidb;
    const int T   = z ? ILEN : SEQ;
    const int tsh = z ? 7 : 10;
    const int zoff= z ? 1024 : 0;
    const int m0 = by*128, n0 = bx*128;

    __shared__ short Xs[128*72];
    __shared__ short Ws[128*72];

    const int tid=threadIdx.x, w=tid>>6, lane=tid&63, quad=lane>>4, nl=lane&15;
    const int wr = w>>1, wc = w&1;
    const int srow = tid >> 3, sch = (tid & 7) * 8;   // staging row (0..31 + 32*rep), short col

    f4 acc[4][4];
    #pragma unroll
    for (int ti=0;ti<4;ti++)
      #pragma unroll
      for (int tj=0;tj<4;tj++) { acc[ti][tj][0]=0.f; acc[ti][tj][1]=0.f; acc[ti][tj][2]=0.f; acc[ti][tj][3]=0.f; }

    uint4 rx[4], rw[4];
    #pragma unroll
    for (int rep=0; rep<4; rep++) {
        const int row = srow + 32*rep;
        rx[rep] = *(const uint4*)&X[(size_t)(m0+row)*HIDDIM + sch];
        rw[rep] = *(const uint4*)&WTall[(size_t)(zoff+n0+row)*HIDDIM + sch];
    }

    for (int k0=0; k0<HIDDIM; k0+=64) {
        __syncthreads();
        #pragma unroll
        for (int rep=0; rep<4; rep++) {
            const int row = srow + 32*rep;
            *(uint4*)&Xs[row*72 + sch] = rx[rep];
            *(uint4*)&Ws[row*72 + sch] = rw[rep];
        }
        __syncthreads();
        if (k0 + 64 < HIDDIM) {
            const int k1 = k0 + 64;
            #pragma unroll
            for (int rep=0; rep<4; rep++) {
                const int row = srow + 32*rep;
                rx[rep] = *(const uint4*)&X[(size_t)(m0+row)*HIDDIM + k1 + sch];
                rw[rep] = *(const uint4*)&WTall[(size_t)(zoff+n0+row)*HIDDIM + k1 + sch];
            }
        }
        bf8 a[4][2], b[4][2];
        #pragma unroll
        for (int ti=0;ti<4;ti++)
          #pragma unroll
          for (int s=0;s<2;s++)
            a[ti][s] = *(const bf8*)&Xs[(64*wr + 16*ti + nl)*72 + s*32 + quad*8];
        #pragma unroll
        for (int tj=0;tj<4;tj++)
          #pragma unroll
          for (int s=0;s<2;s++)
            b[tj][s] = *(const bf8*)&Ws[(64*wc + 16*tj + nl)*72 + s*32 + quad*8];
        #pragma unroll
        for (int ti=0;ti<4;ti++)
          #pragma unroll
          for (int tj=0;tj<4;tj++)
            #pragma unroll
            for (int s=0;s<2;s++)
              acc[ti][tj] = MFMA(a[ti][s], b[tj][s], acc[ti][tj]);
    }

    #pragma unroll
    for (int tj=0;tj<4;tj++) {
        const int n = n0 + 64*wc + 16*tj + nl;
        const int nn = n & 1023;
        const int h = nn >> 6, d = nn & 63;
        float bias; short* outp; int mode;
        if (z==0) {
            if (n < 1024)      { bias = bq[nn]; outp = qo;  mode=0; }
            else if (n < 2048) { bias = bk[nn]; outp = ko;  mode=0; }
            else               { bias = bv[nn]; outp = vTo; mode=1; }
        } else {
            if (n < 1024)      { bias = bk[nn]; outp = iko;  mode=0; }
            else               { bias = bv[nn]; outp = ivTo; mode=1; }
        }
        #pragma unroll
        for (int ti=0;ti<4;ti++) {
            const int mb = m0 + 64*wr + 16*ti + quad*4;
            const int bb = mb >> tsh, tt = mb & (T-1);
            if (mode) {
                bf4 o;
                #pragma unroll
                for (int i=0;i<4;i++) o[i] = f2bf(acc[ti][tj][i] + bias);
                *(bf4*)&outp[((size_t)(bb*NH + h)*SD + d)*T + tt] = o;
            } else {
                #pragma unroll
                for (int i=0;i<4;i++)
                    outp[((size_t)(bb*NH + h)*T + tt + i)*SD + d] = f2bf(acc[ti][tj][i] + bias);
            }
        }
    }
}

// ---------------------------------------------------------------------------
// Fused attention (bf16 MFMA). Per block: (b, h, 64 q-rows), BN=64.
// Register-prefetch pipeline: iter i+1's K/V/E/mask loaded into VGPRs after
// B3 of iter i (latency hidden under softmax+PV); chained into instruct loop.
// Static-shift softmax. Qe via in-wave shfl (exact); Ke bf16 LDS keT[128][68].
// E circular LDS. LDS = 54272 B -> 3 blocks/CU.
// ---------------------------------------------------------------------------
__global__ __launch_bounds__(256,2) void attn_mfma(
    const short* __restrict__ qg, const short* __restrict__ kg, const short* __restrict__ vTg,
    const short* __restrict__ ikg, const short* __restrict__ ivTg,
    const float* __restrict__ mask, const float* __restrict__ imask,
    const float* __restrict__ gate, const short* __restrict__ Ebf,
    float* __restrict__ out)
{
    const int l0 = blockIdx.x * 64, h = blockIdx.y, b = blockIdx.z;
    const int tid = threadIdx.x, w = tid>>6, lane = tid&63, quad = lane>>4, nl = lane&15;
    const int srow = tid >> 3, sch = (tid & 7) * 8;   // staging row, short col

    __shared__ short keT[128*68];     // 17408 B  keT[c][rk] = Ke[rk][c], bf16
    __shared__ short ksh[64*72];      //  9216 B (aliased by ps in main loop)
    __shared__ short vts[64*72];      //  9216 B
    __shared__ short es [128*72];     // 18432 B circular (aliased by psi in instruct)
    short* ps  = ksh;                 // wave-local rows [16w,16w+16)
    short* psi = es;                  // wave-local rows (es dead in instruct loop)

    const size_t bh = (size_t)(b*NH + h);
    const short* kbase   = kg   + bh*SEQ*SD;
    const short* vTbase  = vTg  + bh*SD*SEQ;
    const short* ikbase  = ikg  + bh*ILEN*SD;
    const short* ivTbase = ivTg + bh*SD*ILEN;

    // Q A-fragments: loop-invariant, registers only
    bf8 aq[2];
    {
        const short* qrow = qg + (bh*SEQ + l0 + 16*w + nl)*SD;
        #pragma unroll
        for (int s=0;s<2;s++) aq[s] = *(const bf8*)&qrow[s*32 + quad*8];
    }

    f4 o1[4], o2[4];
    float l1[4], l2[4];
    #pragma unroll
    for (int t=0;t<4;t++) {
        o1[t][0]=0.f;o1[t][1]=0.f;o1[t][2]=0.f;o1[t][3]=0.f;
        o2[t][0]=0.f;o2[t][1]=0.f;o2[t][2]=0.f;o2[t][3]=0.f;
        l1[t]=0.f; l2[t]=0.f;
    }

    // Qe in-wave gather constants
    int srci[4]; bool ci[4];
    #pragma unroll
    for (int i=0;i<4;i++) {
        const int d0 = 4*quad + i - nl;
        srci[i] = (lane & 48) | ((d0 - 1) & 15);
        ci[i]   = (d0 >= 1);
    }

    // ---------------- pipeline prologue: load iter-0 staging data ----------
    uint4 rk0, rk1, rv0, rv1, re0, re1, re2, re3;
    float pmn[4];
    {
        const int jb0 = l0 + 960;
        rk0 = *(const uint4*)&kbase[(size_t)srow*SD + sch];
        rk1 = *(const uint4*)&kbase[(size_t)(srow+32)*SD + sch];
        rv0 = *(const uint4*)&vTbase[(size_t)srow*SEQ + sch];
        rv1 = *(const uint4*)&vTbase[(size_t)(srow+32)*SEQ + sch];
        re0 = *(const uint4*)&Ebf[(size_t)(jb0+srow)*SD + sch];
        re1 = *(const uint4*)&Ebf[(size_t)(jb0+srow+32)*SD + sch];
        re2 = *(const uint4*)&Ebf[(size_t)(jb0+srow+64)*SD + sch];
        re3 = *(const uint4*)&Ebf[(size_t)(jb0+srow+96)*SD + sch];
        #pragma unroll
        for (int t=0;t<4;t++) pmn[t] = mask[b*SEQ + 16*t + nl] - SHIFT;
    }

    // ======================= main attention over S keys =====================
    for (int r0=0; r0<SEQ; r0+=64) {
        const int jb = l0 - r0 + 960;   // E window base row (slides -64/iter)
        float pm[4];
        #pragma unroll
        for (int t=0;t<4;t++) pm[t] = pmn[t];

        __syncthreads();   // B1: prev iter's LDS reads done
        *(uint4*)&ksh[srow*72 + sch]      = rk0;
        *(uint4*)&ksh[(srow+32)*72 + sch] = rk1;
        *(uint4*)&vts[srow*72 + sch]      = rv0;
        *(uint4*)&vts[(srow+32)*72 + sch] = rv1;
        *(uint4*)&es[((jb+srow)&127)*72 + sch]    = re0;
        *(uint4*)&es[((jb+srow+32)&127)*72 + sch] = re1;
        if (r0 == 0) {
            *(uint4*)&es[((jb+srow+64)&127)*72 + sch] = re2;
            *(uint4*)&es[((jb+srow+96)&127)*72 + sch] = re3;
        }
        __syncthreads();   // B2: staging visible

        bf8 ak[2];
        #pragma unroll
        for (int s=0;s<2;s++) ak[s] = *(const bf8*)&ksh[(16*w+nl)*72 + s*32 + quad*8];
        // QK^T
        f4 sc[4];
        #pragma unroll
        for (int t=0;t<4;t++) { sc[t][0]=0.f; sc[t][1]=0.f; sc[t][2]=0.f; sc[t][3]=0.f; }
        #pragma unroll
        for (int t=0;t<4;t++)
            #pragma unroll
            for (int s=0;s<2;s++) {
                bf8 bk = *(const bf8*)&ksh[(16*t+nl)*72 + s*32 + quad*8];
                sc[t] = MFMA(aq[s], bk, sc[t]);
            }
        // pruned band matmuls: wave w: Qe tiles {w..w+4}, Ke tiles {3-w..7-w}
        f4 qe[5], ke[5];
        #pragma unroll
        for (int j=0;j<5;j++) {
            qe[j][0]=0.f;qe[j][1]=0.f;qe[j][2]=0.f;qe[j][3]=0.f;
            ke[j][0]=0.f;ke[j][1]=0.f;ke[j][2]=0.f;ke[j][3]=0.f;
        }
        #pragma unroll
        for (int j=0;j<5;j++) {
            const int sq = (jb + 16*(w+j)   + nl) & 127;
            const int sk = (jb + 16*(3-w+j) + nl) & 127;
            #pragma unroll
            for (int s=0;s<2;s++) {
                bf8 beq = *(const bf8*)&es[sq*72 + s*32 + quad*8];
                bf8 bek = *(const bf8*)&es[sk*72 + s*32 + quad*8];
                qe[j] = MFMA(aq[s], beq, qe[j]);
                ke[j] = MFMA(ak[s], bek, ke[j]);
            }
        }
        // Ke band -> LDS bf16
        {
            const int rb = 16*w + 4*quad;
            #pragma unroll
            for (int j=0;j<5;j++) {
                const int c = 16*(3-w+j) + nl;
                bf4 pk;
                #pragma unroll
                for (int i=0;i<4;i++) pk[i] = f2bf(ke[j][i]);
                *(bf4*)&keT[c*68 + rb] = pk;
            }
        }
        __syncthreads();   // B3: keT visible; ksh reads drained (ps may alias)

        // prefetch next iteration's staging data (latency hidden by softmax+PV)
        if (r0 + 64 < SEQ) {
            const int r1 = r0 + 64, jbn = jb - 64;
            rk0 = *(const uint4*)&kbase[(size_t)(r1+srow)*SD + sch];
            rk1 = *(const uint4*)&kbase[(size_t)(r1+srow+32)*SD + sch];
            rv0 = *(const uint4*)&vTbase[(size_t)srow*SEQ + r1 + sch];
            rv1 = *(const uint4*)&vTbase[(size_t)(srow+32)*SEQ + r1 + sch];
            re0 = *(const uint4*)&Ebf[(size_t)(jbn+srow)*SD + sch];
            re1 = *(const uint4*)&Ebf[(size_t)(jbn+srow+32)*SD + sch];
            #pragma unroll
            for (int t=0;t<4;t++) pmn[t] = mask[b*SEQ + r1 + 16*t + nl] - SHIFT;
        } else {           // chain into instruct loop iter 0
            rk0 = *(const uint4*)&ikbase[(size_t)srow*SD + sch];
            rk1 = *(const uint4*)&ikbase[(size_t)(srow+32)*SD + sch];
            rv0 = *(const uint4*)&ivTbase[(size_t)srow*ILEN + sch];
            rv1 = *(const uint4*)&ivTbase[(size_t)(srow+32)*ILEN + sch];
            #pragma unroll
            for (int t=0;t<4;t++) pmn[t] = imask[b*ILEN + 16*t + nl] - SHIFT;
        }

        // scores -> p = exp(s - SHIFT); per-lane partial row sums
        short pbf[4][4];
        #pragma unroll
        for (int i=0;i<4;i++) {
            const int li = 16*w + 4*quad + i;
            #pragma unroll
            for (int t=0;t<4;t++) {
                float v = ci[i] ? qe[4-t][i] : qe[3-t][i];
                const float qadd = __shfl(v, srci[i]);
                const int ri = 16*t + nl;
                const float kadd = bf2f(keT[(li - ri + 63)*68 + ri]);
                const float sval = (sc[t][i] + qadd + kadd)*0.125f + pm[t];
                const float p = __expf(sval);
                pbf[i][t] = f2bf(p);
                l1[i] += p;
            }
        }
        // ps (alias ksh) wave-local rows [16w,16w+16)
        #pragma unroll
        for (int i=0;i<4;i++) {
            const int li = 16*w + quad*4 + i;
            #pragma unroll
            for (int t=0;t<4;t++) ps[li*72 + 16*t + nl] = pbf[i][t];
        }
        // PV
        #pragma unroll
        for (int s=0;s<2;s++) {
            bf8 ap = *(const bf8*)&ps[(16*w+nl)*72 + s*32 + quad*8];
            #pragma unroll
            for (int t=0;t<4;t++) {
                bf8 bv = *(const bf8*)&vts[(16*t+nl)*72 + s*32 + quad*8];
                o1[t] = MFMA(ap, bv, o1[t]);
            }
        }
    }

    // ==================== instruct attention over L keys ====================
    for (int r0=0; r0<ILEN; r0+=64) {
        float im[4];
        #pragma unroll
        for (int t=0;t<4;t++) im[t] = pmn[t];

        __syncthreads();
        *(uint4*)&ksh[srow*72 + sch]      = rk0;
        *(uint4*)&ksh[(srow+32)*72 + sch] = rk1;
        *(uint4*)&vts[srow*72 + sch]      = rv0;
        *(uint4*)&vts[(srow+32)*72 + sch] = rv1;
        __syncthreads();

        if (r0 == 0) {     // prefetch instruct iter 1
            rk0 = *(const uint4*)&ikbase[(size_t)(64+srow)*SD + sch];
            rk1 = *(const uint4*)&ikbase[(size_t)(64+srow+32)*SD + sch];
            rv0 = *(const uint4*)&ivTbase[(size_t)srow*ILEN + 64 + sch];
            rv1 = *(const uint4*)&ivTbase[(size_t)(srow+32)*ILEN + 64 + sch];
            #pragma unroll
            for (int t=0;t<4;t++) pmn[t] = imask[b*ILEN + 64 + 16*t + nl] - SHIFT;
        }

        f4 sc[4];
        #pragma unroll
        for (int t=0;t<4;t++) { sc[t][0]=0.f; sc[t][1]=0.f; sc[t][2]=0.f; sc[t][3]=0.f; }
        #pragma unroll
        for (int t=0;t<4;t++)
            #pragma unroll
            for (int s=0;s<2;s++) {
                bf8 bk = *(const bf8*)&ksh[(16*t+nl)*72 + s*32 + quad*8];
                sc[t] = MFMA(aq[s], bk, sc[t]);
            }
        short pbf[4][4];
        #pragma unroll
        for (int t=0;t<4;t++) {
            #pragma unroll
            for (int i=0;i<4;i++) {
                const float p = __expf(sc[t][i]*0.125f + im[t]);
                pbf[i][t] = f2bf(p);
                l2[i] += p;
            }
        }
        // psi (alias es, dead here): wave-local rows
        #pragma unroll
        for (int i=0;i<4;i++) {
            const int li = 16*w + quad*4 + i;
            #pragma unroll
            for (int t=0;t<4;t++) psi[li*72 + 16*t + nl] = pbf[i][t];
        }
        #pragma unroll
        for (int s=0;s<2;s++) {
            bf8 ap = *(const bf8*)&psi[(16*w+nl)*72 + s*32 + quad*8];
            #pragma unroll
            for (int t=0;t<4;t++) {
                bf8 bv = *(const bf8*)&vts[(16*t+nl)*72 + s*32 + quad*8];
                o2[t] = MFMA(ap, bv, o2[t]);
            }
        }
    }

    // ====================== final row-sum reductions ========================
    #pragma unroll
    for (int i=0;i<4;i++) {
        #pragma unroll
        for (int off=1; off<16; off<<=1) {
            l1[i] += __shfl_xor(l1[i], off);
            l2[i] += __shfl_xor(l2[i], off);
        }
    }

    // ============================== epilogue ================================
    const float tg = tanhf(gate[h]);
    #pragma unroll
    for (int i=0;i<4;i++) {
        const int l = l0 + 16*w + quad*4 + i;
        const float inv1 = 1.0f/l1[i], inv2 = 1.0f/l2[i];
        #pragma unroll
        for (int t=0;t<4;t++) {
            const int d = 16*t + nl;
            out[((size_t)(b*SEQ + l)*NH + h)*SD + d] = o1[t][i]*inv1 + tg*(o2[t][i]*inv2);
        }
    }
}

extern "C" void kernel_launch(void* const* d_in, const int* in_sizes, int n_in,
                              void* d_out, int out_size, void* d_ws, size_t ws_size,
                              hipStream_t stream) {
    const float* hidden  = (const float*)d_in[0];
    const float* mask    = (const float*)d_in[1];
    const float* ihidden = (const float*)d_in[2];
    const float* imask   = (const float*)d_in[3];
    const float* Wq   = (const float*)d_in[4];
    const float* bq   = (const float*)d_in[5];
    const float* Wk   = (const float*)d_in[6];
    const float* bk   = (const float*)d_in[7];
    const float* Wv   = (const float*)d_in[8];
    const float* bv   = (const float*)d_in[9];
    const float* gate = (const float*)d_in[10];
    const float* dist = (const float*)d_in[11];
    float* out = (float*)d_out;

    short* ws = (short*)d_ws;
    const size_t OFF_INS = N_HID;
    const size_t OFF_E   = OFF_INS + N_INS;
    const size_t OFF_WT  = OFF_E + N_E;
    const size_t OFF_Q   = OFF_WT + 3*(size_t)N_W;
    const size_t OFF_K   = OFF_Q + N_HID;
    const size_t OFF_VT  = OFF_K + N_HID;
    const size_t OFF_IK  = OFF_VT + N_HID;
    const size_t OFF_IVT = OFF_IK + N_INS;

    cast_flat<<<4736, 256, 0, stream>>>(hidden, ihidden, dist, ws);
    cast_wt<<<dim3(16,16,3), 256, 0, stream>>>(Wq, Wk, Wv, ws + OFF_WT);
    proj_mfma<<<dim3(24,32,2), 256, 0, stream>>>(
        ws, ws + OFF_INS, ws + OFF_WT,
        bq, bk, bv,
        ws + OFF_Q, ws + OFF_K, ws + OFF_VT, ws + OFF_IK, ws + OFF_IVT);
    attn_mfma<<<dim3(16,16,4), 256, 0, stream>>>(
        ws + OFF_Q, ws + OFF_K, ws + OFF_VT, ws + OFF_IK, ws + OFF_IVT,
        mask, imask, gate, ws + OFF_E, out);
}

// Round 10
// 251.706 us; speedup vs baseline: 1.3792x; 1.3792x over previous
//
#include <hip/hip_runtime.h>
#include <cmath>

#define NB 4
#define NH 16
#define SD 64
#define SEQ 1024
#define ILEN 128
#define HIDDIM 1024

#define N_HID (NB*SEQ*HIDDIM)     // 4194304
#define N_INS (NB*ILEN*HIDDIM)    // 524288
#define N_E_SRC (2047*SD)         // 131008
#define N_E   (2048*SD)           // 131072 (incl zero pad row)
#define N_W   (HIDDIM*HIDDIM)     // 1048576

typedef short bf8 __attribute__((ext_vector_type(8)));
typedef short bf4 __attribute__((ext_vector_type(4)));
typedef float f4  __attribute__((ext_vector_type(4)));

#define MFMA(a,b,c) __builtin_amdgcn_mfma_f32_16x16x32_bf16(a,b,c,0,0,0)

// static softmax shift (R8-verified): shift-invariant, logits O(1).
#define SHIFT 12.0f

__device__ __forceinline__ float bf2f(short s) {
    unsigned u = ((unsigned)(unsigned short)s) << 16;
    return __uint_as_float(u);
}
__device__ __forceinline__ short f2bf(float x) {          // RNE
    unsigned u = __float_as_uint(x);
    u = (u + 0x7FFFu + ((u >> 16) & 1u)) >> 16;
    return (short)u;
}

// ---------------------------------------------------------------------------
// Cast fp32 -> bf16: hidden, instruct, dist_emb (+1 zero pad row for E)
// ---------------------------------------------------------------------------
__global__ __launch_bounds__(256) void cast_flat(
    const float* __restrict__ hid, const float* __restrict__ ins,
    const float* __restrict__ E, short* __restrict__ ws)
{
    int i = (blockIdx.x * 256 + threadIdx.x) * 4;
    short* dhid = ws;
    short* dins = ws + N_HID;
    short* dE   = ws + N_HID + N_INS;
    if (i < N_HID) {
        float4 v = *(const float4*)&hid[i];
        bf4 o; o[0]=f2bf(v.x); o[1]=f2bf(v.y); o[2]=f2bf(v.z); o[3]=f2bf(v.w);
        *(bf4*)&dhid[i] = o;
    } else if (i < N_HID + N_INS) {
        int j = i - N_HID;
        float4 v = *(const float4*)&ins[j];
        bf4 o; o[0]=f2bf(v.x); o[1]=f2bf(v.y); o[2]=f2bf(v.z); o[3]=f2bf(v.w);
        *(bf4*)&dins[j] = o;
    } else {
        int j = i - N_HID - N_INS;
        if (j < N_E) {
            bf4 o;
            if (j < N_E_SRC) {
                float4 v = *(const float4*)&E[j];
                o[0]=f2bf(v.x); o[1]=f2bf(v.y); o[2]=f2bf(v.z); o[3]=f2bf(v.w);
            } else {
                o[0]=0; o[1]=0; o[2]=0; o[3]=0;
            }
            *(bf4*)&dE[j] = o;
        }
    }
}

// ---------------------------------------------------------------------------
// Cast + transpose W -> WT bf16 (WT[n][k] = W[k][n]); grid (16,16,3)
// ---------------------------------------------------------------------------
__global__ __launch_bounds__(256) void cast_wt(
    const float* __restrict__ Wq, const float* __restrict__ Wk,
    const float* __restrict__ Wv, short* __restrict__ dstbase)
{
    const float* W = (blockIdx.z==0) ? Wq : (blockIdx.z==1) ? Wk : Wv;
    short* dst = dstbase + (size_t)blockIdx.z * N_W;
    const int k0 = blockIdx.y*64, n0 = blockIdx.x*64;
    __shared__ float st[64][65];
    const int tid = threadIdx.x;
    #pragma unroll
    for (int rep=0; rep<4; rep++) {
        int u = tid + rep*256;
        int row = u >> 4, col = (u & 15) * 4;
        float4 v = *(const float4*)&W[(size_t)(k0+row)*HIDDIM + n0 + col];
        st[row][col+0]=v.x; st[row][col+1]=v.y; st[row][col+2]=v.z; st[row][col+3]=v.w;
    }
    __syncthreads();
    #pragma unroll
    for (int rep=0; rep<4; rep++) {
        int u = tid + rep*256;
        int nrow = u >> 4, kc = (u & 15) * 4;
        bf4 o;
        #pragma unroll
        for (int j=0;j<4;j++) o[j] = f2bf(st[kc+j][nrow]);
        *(bf4*)&dst[(size_t)(n0+nrow)*HIDDIM + k0 + kc] = o;
    }
}

// ---------------------------------------------------------------------------
// Fused projection GEMM (bf16 MFMA), 128x128 tiles, BK=64, 4 waves (2x2).
// R8-exact (NO register prefetch: R9 showed it spills under the compiler's
// ~128-VGPR occupancy target -> 190 MB scratch traffic, 1.6x slower).
// ---------------------------------------------------------------------------
__global__ __launch_bounds__(256) void proj_mfma(
    const short* __restrict__ hidb, const short* __restrict__ insb,
    const short* __restrict__ WTall,
    const float* __restrict__ bq, const float* __restrict__ bk, const float* __restrict__ bv,
    short* __restrict__ qo, short* __restrict__ ko, short* __restrict__ vTo,
    short* __restrict__ iko, short* __restrict__ ivTo)
{
    const int z = blockIdx.z;
    const int bx = blockIdx.x, by = blockIdx.y;
    if (z==1 && (bx>=16 || by>=4)) return;
    const short* X = z ? insb : hidb;
    const int T   = z ? ILEN : SEQ;
    const int tsh = z ? 7 : 10;
    const int zoff= z ? 1024 : 0;
    const int m0 = by*128, n0 = bx*128;

    __shared__ short Xs[128*72];
    __shared__ short Ws[128*72];

    const int tid=threadIdx.x, w=tid>>6, lane=tid&63, quad=lane>>4, nl=lane&15;
    const int wr = w>>1, wc = w&1;

    f4 acc[4][4];
    #pragma unroll
    for (int ti=0;ti<4;ti++)
      #pragma unroll
      for (int tj=0;tj<4;tj++) { acc[ti][tj][0]=0.f; acc[ti][tj][1]=0.f; acc[ti][tj][2]=0.f; acc[ti][tj][3]=0.f; }

    for (int k0=0; k0<HIDDIM; k0+=64) {
        __syncthreads();
        #pragma unroll
        for (int rep=0; rep<4; rep++) {
            int u = tid + rep*256;
            int row = u >> 3, ch = u & 7;
            *(uint4*)&Xs[row*72 + ch*8] = *(const uint4*)&X[(size_t)(m0+row)*HIDDIM + k0 + ch*8];
            *(uint4*)&Ws[row*72 + ch*8] = *(const uint4*)&WTall[(size_t)(zoff+n0+row)*HIDDIM + k0 + ch*8];
        }
        __syncthreads();
        bf8 a[4][2], b[4][2];
        #pragma unroll
        for (int ti=0;ti<4;ti++)
          #pragma unroll
          for (int s=0;s<2;s++)
            a[ti][s] = *(const bf8*)&Xs[(64*wr + 16*ti + nl)*72 + s*32 + quad*8];
        #pragma unroll
        for (int tj=0;tj<4;tj++)
          #pragma unroll
          for (int s=0;s<2;s++)
            b[tj][s] = *(const bf8*)&Ws[(64*wc + 16*tj + nl)*72 + s*32 + quad*8];
        #pragma unroll
        for (int ti=0;ti<4;ti++)
          #pragma unroll
          for (int tj=0;tj<4;tj++)
            #pragma unroll
            for (int s=0;s<2;s++)
              acc[ti][tj] = MFMA(a[ti][s], b[tj][s], acc[ti][tj]);
    }

    #pragma unroll
    for (int tj=0;tj<4;tj++) {
        const int n = n0 + 64*wc + 16*tj + nl;
        const int nn = n & 1023;
        const int h = nn >> 6, d = nn & 63;
        float bias; short* outp; int mode;
        if (z==0) {
            if (n < 1024)      { bias = bq[nn]; outp = qo;  mode=0; }
            else if (n < 2048) { bias = bk[nn]; outp = ko;  mode=0; }
            else               { bias = bv[nn]; outp = vTo; mode=1; }
        } else {
            if (n < 1024)      { bias = bk[nn]; outp = iko;  mode=0; }
            else               { bias = bv[nn]; outp = ivTo; mode=1; }
        }
        #pragma unroll
        for (int ti=0;ti<4;ti++) {
            const int mb = m0 + 64*wr + 16*ti + quad*4;
            const int bb = mb >> tsh, tt = mb & (T-1);
            if (mode) {
                bf4 o;
                #pragma unroll
                for (int i=0;i<4;i++) o[i] = f2bf(acc[ti][tj][i] + bias);
                *(bf4*)&outp[((size_t)(bb*NH + h)*SD + d)*T + tt] = o;
            } else {
                #pragma unroll
                for (int i=0;i<4;i++)
                    outp[((size_t)(bb*NH + h)*T + tt + i)*SD + d] = f2bf(acc[ti][tj][i] + bias);
            }
        }
    }
}

// ---------------------------------------------------------------------------
// Fused attention (bf16 MFMA). Per block: (b, h, 64 q-rows), BN=64.
// Register-prefetch pipeline: iter i+1's K/V/E/mask loaded into VGPRs after
// B3 of iter i (latency hidden under softmax+PV); chained into instruct loop.
// Static-shift softmax. Qe via in-wave shfl (exact); Ke bf16 LDS keT[128][68].
// E circular LDS. LDS = 54272 B -> 3 blocks/CU.
// ---------------------------------------------------------------------------
__global__ __launch_bounds__(256,2) void attn_mfma(
    const short* __restrict__ qg, const short* __restrict__ kg, const short* __restrict__ vTg,
    const short* __restrict__ ikg, const short* __restrict__ ivTg,
    const float* __restrict__ mask, const float* __restrict__ imask,
    const float* __restrict__ gate, const short* __restrict__ Ebf,
    float* __restrict__ out)
{
    const int l0 = blockIdx.x * 64, h = blockIdx.y, b = blockIdx.z;
    const int tid = threadIdx.x, w = tid>>6, lane = tid&63, quad = lane>>4, nl = lane&15;
    const int srow = tid >> 3, sch = (tid & 7) * 8;   // staging row, short col

    __shared__ short keT[128*68];     // 17408 B  keT[c][rk] = Ke[rk][c], bf16
    __shared__ short ksh[64*72];      //  9216 B (aliased by ps in main loop)
    __shared__ short vts[64*72];      //  9216 B
    __shared__ short es [128*72];     // 18432 B circular (aliased by psi in instruct)
    short* ps  = ksh;                 // wave-local rows [16w,16w+16)
    short* psi = es;                  // wave-local rows (es dead in instruct loop)

    const size_t bh = (size_t)(b*NH + h);
    const short* kbase   = kg   + bh*SEQ*SD;
    const short* vTbase  = vTg  + bh*SD*SEQ;
    const short* ikbase  = ikg  + bh*ILEN*SD;
    const short* ivTbase = ivTg + bh*SD*ILEN;

    // Q A-fragments: loop-invariant, registers only
    bf8 aq[2];
    {
        const short* qrow = qg + (bh*SEQ + l0 + 16*w + nl)*SD;
        #pragma unroll
        for (int s=0;s<2;s++) aq[s] = *(const bf8*)&qrow[s*32 + quad*8];
    }

    f4 o1[4], o2[4];
    float l1[4], l2[4];
    #pragma unroll
    for (int t=0;t<4;t++) {
        o1[t][0]=0.f;o1[t][1]=0.f;o1[t][2]=0.f;o1[t][3]=0.f;
        o2[t][0]=0.f;o2[t][1]=0.f;o2[t][2]=0.f;o2[t][3]=0.f;
        l1[t]=0.f; l2[t]=0.f;
    }

    // Qe in-wave gather constants
    int srci[4]; bool ci[4];
    #pragma unroll
    for (int i=0;i<4;i++) {
        const int d0 = 4*quad + i - nl;
        srci[i] = (lane & 48) | ((d0 - 1) & 15);
        ci[i]   = (d0 >= 1);
    }

    // ---------------- pipeline prologue: load iter-0 staging data ----------
    uint4 rk0, rk1, rv0, rv1, re0, re1, re2, re3;
    float pmn[4];
    {
        const int jb0 = l0 + 960;
        rk0 = *(const uint4*)&kbase[(size_t)srow*SD + sch];
        rk1 = *(const uint4*)&kbase[(size_t)(srow+32)*SD + sch];
        rv0 = *(const uint4*)&vTbase[(size_t)srow*SEQ + sch];
        rv1 = *(const uint4*)&vTbase[(size_t)(srow+32)*SEQ + sch];
        re0 = *(const uint4*)&Ebf[(size_t)(jb0+srow)*SD + sch];
        re1 = *(const uint4*)&Ebf[(size_t)(jb0+srow+32)*SD + sch];
        re2 = *(const uint4*)&Ebf[(size_t)(jb0+srow+64)*SD + sch];
        re3 = *(const uint4*)&Ebf[(size_t)(jb0+srow+96)*SD + sch];
        #pragma unroll
        for (int t=0;t<4;t++) pmn[t] = mask[b*SEQ + 16*t + nl] - SHIFT;
    }

    // ======================= main attention over S keys =====================
    for (int r0=0; r0<SEQ; r0+=64) {
        const int jb = l0 - r0 + 960;   // E window base row (slides -64/iter)
        float pm[4];
        #pragma unroll
        for (int t=0;t<4;t++) pm[t] = pmn[t];

        __syncthreads();   // B1: prev iter's LDS reads done
        *(uint4*)&ksh[srow*72 + sch]      = rk0;
        *(uint4*)&ksh[(srow+32)*72 + sch] = rk1;
        *(uint4*)&vts[srow*72 + sch]      = rv0;
        *(uint4*)&vts[(srow+32)*72 + sch] = rv1;
        *(uint4*)&es[((jb+srow)&127)*72 + sch]    = re0;
        *(uint4*)&es[((jb+srow+32)&127)*72 + sch] = re1;
        if (r0 == 0) {
            *(uint4*)&es[((jb+srow+64)&127)*72 + sch] = re2;
            *(uint4*)&es[((jb+srow+96)&127)*72 + sch] = re3;
        }
        __syncthreads();   // B2: staging visible

        bf8 ak[2];
        #pragma unroll
        for (int s=0;s<2;s++) ak[s] = *(const bf8*)&ksh[(16*w+nl)*72 + s*32 + quad*8];
        // QK^T
        f4 sc[4];
        #pragma unroll
        for (int t=0;t<4;t++) { sc[t][0]=0.f; sc[t][1]=0.f; sc[t][2]=0.f; sc[t][3]=0.f; }
        #pragma unroll
        for (int t=0;t<4;t++)
            #pragma unroll
            for (int s=0;s<2;s++) {
                bf8 bk = *(const bf8*)&ksh[(16*t+nl)*72 + s*32 + quad*8];
                sc[t] = MFMA(aq[s], bk, sc[t]);
            }
        // pruned band matmuls: wave w: Qe tiles {w..w+4}, Ke tiles {3-w..7-w}
        f4 qe[5], ke[5];
        #pragma unroll
        for (int j=0;j<5;j++) {
            qe[j][0]=0.f;qe[j][1]=0.f;qe[j][2]=0.f;qe[j][3]=0.f;
            ke[j][0]=0.f;ke[j][1]=0.f;ke[j][2]=0.f;ke[j][3]=0.f;
        }
        #pragma unroll
        for (int j=0;j<5;j++) {
            const int sq = (jb + 16*(w+j)   + nl) & 127;
            const int sk = (jb + 16*(3-w+j) + nl) & 127;
            #pragma unroll
            for (int s=0;s<2;s++) {
                bf8 beq = *(const bf8*)&es[sq*72 + s*32 + quad*8];
                bf8 bek = *(const bf8*)&es[sk*72 + s*32 + quad*8];
                qe[j] = MFMA(aq[s], beq, qe[j]);
                ke[j] = MFMA(ak[s], bek, ke[j]);
            }
        }
        // Ke band -> LDS bf16
        {
            const int rb = 16*w + 4*quad;
            #pragma unroll
            for (int j=0;j<5;j++) {
                const int c = 16*(3-w+j) + nl;
                bf4 pk;
                #pragma unroll
                for (int i=0;i<4;i++) pk[i] = f2bf(ke[j][i]);
                *(bf4*)&keT[c*68 + rb] = pk;
            }
        }
        __syncthreads();   // B3: keT visible; ksh reads drained (ps may alias)

        // prefetch next iteration's staging data (latency hidden by softmax+PV)
        if (r0 + 64 < SEQ) {
            const int r1 = r0 + 64, jbn = jb - 64;
            rk0 = *(const uint4*)&kbase[(size_t)(r1+srow)*SD + sch];
            rk1 = *(const uint4*)&kbase[(size_t)(r1+srow+32)*SD + sch];
            rv0 = *(const uint4*)&vTbase[(size_t)srow*SEQ + r1 + sch];
            rv1 = *(const uint4*)&vTbase[(size_t)(srow+32)*SEQ + r1 + sch];
            re0 = *(const uint4*)&Ebf[(size_t)(jbn+srow)*SD + sch];
            re1 = *(const uint4*)&Ebf[(size_t)(jbn+srow+32)*SD + sch];
            #pragma unroll
            for (int t=0;t<4;t++) pmn[t] = mask[b*SEQ + r1 + 16*t + nl] - SHIFT;
        } else {           // chain into instruct loop iter 0
            rk0 = *(const uint4*)&ikbase[(size_t)srow*SD + sch];
            rk1 = *(const uint4*)&ikbase[(size_t)(srow+32)*SD + sch];
            rv0 = *(const uint4*)&ivTbase[(size_t)srow*ILEN + sch];
            rv1 = *(const uint4*)&ivTbase[(size_t)(srow+32)*ILEN + sch];
            #pragma unroll
            for (int t=0;t<4;t++) pmn[t] = imask[b*ILEN + 16*t + nl] - SHIFT;
        }

        // scores -> p = exp(s - SHIFT); per-lane partial row sums
        short pbf[4][4];
        #pragma unroll
        for (int i=0;i<4;i++) {
            const int li = 16*w + 4*quad + i;
            #pragma unroll
            for (int t=0;t<4;t++) {
                float v = ci[i] ? qe[4-t][i] : qe[3-t][i];
                const float qadd = __shfl(v, srci[i]);
                const int ri = 16*t + nl;
                const float kadd = bf2f(keT[(li - ri + 63)*68 + ri]);
                const float sval = (sc[t][i] + qadd + kadd)*0.125f + pm[t];
                const float p = __expf(sval);
                pbf[i][t] = f2bf(p);
                l1[i] += p;
            }
        }
        // ps (alias ksh) wave-local rows [16w,16w+16)
        #pragma unroll
        for (int i=0;i<4;i++) {
            const int li = 16*w + quad*4 + i;
            #pragma unroll
            for (int t=0;t<4;t++) ps[li*72 + 16*t + nl] = pbf[i][t];
        }
        // PV
        #pragma unroll
        for (int s=0;s<2;s++) {
            bf8 ap = *(const bf8*)&ps[(16*w+nl)*72 + s*32 + quad*8];
            #pragma unroll
            for (int t=0;t<4;t++) {
                bf8 bv = *(const bf8*)&vts[(16*t+nl)*72 + s*32 + quad*8];
                o1[t] = MFMA(ap, bv, o1[t]);
            }
        }
    }

    // ==================== instruct attention over L keys ====================
    for (int r0=0; r0<ILEN; r0+=64) {
        float im[4];
        #pragma unroll
        for (int t=0;t<4;t++) im[t] = pmn[t];

        __syncthreads();
        *(uint4*)&ksh[srow*72 + sch]      = rk0;
        *(uint4*)&ksh[(srow+32)*72 + sch] = rk1;
        *(uint4*)&vts[srow*72 + sch]      = rv0;
        *(uint4*)&vts[(srow+32)*72 + sch] = rv1;
        __syncthreads();

        if (r0 == 0) {     // prefetch instruct iter 1
            rk0 = *(const uint4*)&ikbase[(size_t)(64+srow)*SD + sch];
            rk1 = *(const uint4*)&ikbase[(size_t)(64+srow+32)*SD + sch];
            rv0 = *(const uint4*)&ivTbase[(size_t)srow*ILEN + 64 + sch];
            rv1 = *(const uint4*)&ivTbase[(size_t)(srow+32)*ILEN + 64 + sch];
            #pragma unroll
            for (int t=0;t<4;t++) pmn[t] = imask[b*ILEN + 64 + 16*t + nl] - SHIFT;
        }

        f4 sc[4];
        #pragma unroll
        for (int t=0;t<4;t++) { sc[t][0]=0.f; sc[t][1]=0.f; sc[t][2]=0.f; sc[t][3]=0.f; }
        #pragma unroll
        for (int t=0;t<4;t++)
            #pragma unroll
            for (int s=0;s<2;s++) {
                bf8 bk = *(const bf8*)&ksh[(16*t+nl)*72 + s*32 + quad*8];
                sc[t] = MFMA(aq[s], bk, sc[t]);
            }
        short pbf[4][4];
        #pragma unroll
        for (int t=0;t<4;t++) {
            #pragma unroll
            for (int i=0;i<4;i++) {
                const float p = __expf(sc[t][i]*0.125f + im[t]);
                pbf[i][t] = f2bf(p);
                l2[i] += p;
            }
        }
        // psi (alias es, dead here): wave-local rows
        #pragma unroll
        for (int i=0;i<4;i++) {
            const int li = 16*w + quad*4 + i;
            #pragma unroll
            for (int t=0;t<4;t++) psi[li*72 + 16*t + nl] = pbf[i][t];
        }
        #pragma unroll
        for (int s=0;s<2;s++) {
            bf8 ap = *(const bf8*)&psi[(16*w+nl)*72 + s*32 + quad*8];
            #pragma unroll
            for (int t=0;t<4;t++) {
                bf8 bv = *(const bf8*)&vts[(16*t+nl)*72 + s*32 + quad*8];
                o2[t] = MFMA(ap, bv, o2[t]);
            }
        }
    }

    // ====================== final row-sum reductions ========================
    #pragma unroll
    for (int i=0;i<4;i++) {
        #pragma unroll
        for (int off=1; off<16; off<<=1) {
            l1[i] += __shfl_xor(l1[i], off);
            l2[i] += __shfl_xor(l2[i], off);
        }
    }

    // ============================== epilogue ================================
    const float tg = tanhf(gate[h]);
    #pragma unroll
    for (int i=0;i<4;i++) {
        const int l = l0 + 16*w + quad*4 + i;
        const float inv1 = 1.0f/l1[i], inv2 = 1.0f/l2[i];
        #pragma unroll
        for (int t=0;t<4;t++) {
            const int d = 16*t + nl;
            out[((size_t)(b*SEQ + l)*NH + h)*SD + d] = o1[t][i]*inv1 + tg*(o2[t][i]*inv2);
        }
    }
}

extern "C" void kernel_launch(void* const* d_in, const int* in_sizes, int n_in,
                              void* d_out, int out_size, void* d_ws, size_t ws_size,
                              hipStream_t stream) {
    const float* hidden  = (const float*)d_in[0];
    const float* mask    = (const float*)d_in[1];
    const float* ihidden = (const float*)d_in[2];
    const float* imask   = (const float*)d_in[3];
    const float* Wq   = (const float*)d_in[4];
    const float* bq   = (const float*)d_in[5];
    const float* Wk   = (const float*)d_in[6];
    const float* bk   = (const float*)d_in[7];
    const float* Wv   = (const float*)d_in[8];
    const float* bv   = (const float*)d_in[9];
    const float* gate = (const float*)d_in[10];
    const float* dist = (const float*)d_in[11];
    float* out = (float*)d_out;

    short* ws = (short*)d_ws;
    const size_t OFF_INS = N_HID;
    const size_t OFF_E   = OFF_INS + N_INS;
    const size_t OFF_WT  = OFF_E + N_E;
    const size_t OFF_Q   = OFF_WT + 3*(size_t)N_W;
    const size_t OFF_K   = OFF_Q + N_HID;
    const size_t OFF_VT  = OFF_K + N_HID;
    const size_t OFF_IK  = OFF_VT + N_HID;
    const size_t OFF_IVT = OFF_IK + N_INS;

    cast_flat<<<4736, 256, 0, stream>>>(hidden, ihidden, dist, ws);
    cast_wt<<<dim3(16,16,3), 256, 0, stream>>>(Wq, Wk, Wv, ws + OFF_WT);
    proj_mfma<<<dim3(24,32,2), 256, 0, stream>>>(
        ws, ws + OFF_INS, ws + OFF_WT,
        bq, bk, bv,
        ws + OFF_Q, ws + OFF_K, ws + OFF_VT, ws + OFF_IK, ws + OFF_IVT);
    attn_mfma<<<dim3(16,16,4), 256, 0, stream>>>(
        ws + OFF_Q, ws + OFF_K, ws + OFF_VT, ws + OFF_IK, ws + OFF_IVT,
        mask, imask, gate, ws + OFF_E, out);
}

// Round 11
// 239.690 us; speedup vs baseline: 1.4484x; 1.0501x over previous
//
#include <hip/hip_runtime.h>
#include <cmath>

#define NB 4
#define NH 16
#define SD 64
#define SEQ 1024
#define ILEN 128
#define HIDDIM 1024

#define N_HID (NB*SEQ*HIDDIM)     // 4194304
#define N_INS (NB*ILEN*HIDDIM)    // 524288
#define N_E_SRC (2047*SD)         // 131008
#define N_E   (2048*SD)           // 131072 (incl zero pad row)
#define N_W   (HIDDIM*HIDDIM)     // 1048576

typedef short bf8 __attribute__((ext_vector_type(8)));
typedef short bf4 __attribute__((ext_vector_type(4)));
typedef float f4  __attribute__((ext_vector_type(4)));

#define MFMA(a,b,c) __builtin_amdgcn_mfma_f32_16x16x32_bf16(a,b,c,0,0,0)

// static softmax shift (R8-verified): shift-invariant, logits O(1).
#define SHIFT 12.0f

__device__ __forceinline__ float bf2f(short s) {
    unsigned u = ((unsigned)(unsigned short)s) << 16;
    return __uint_as_float(u);
}
__device__ __forceinline__ short f2bf(float x) {          // RNE
    unsigned u = __float_as_uint(x);
    u = (u + 0x7FFFu + ((u >> 16) & 1u)) >> 16;
    return (short)u;
}

// ---------------------------------------------------------------------------
// Cast fp32 -> bf16: hidden, instruct, dist_emb (+1 zero pad row for E)
// ---------------------------------------------------------------------------
__global__ __launch_bounds__(256) void cast_flat(
    const float* __restrict__ hid, const float* __restrict__ ins,
    const float* __restrict__ E, short* __restrict__ ws)
{
    int i = (blockIdx.x * 256 + threadIdx.x) * 4;
    short* dhid = ws;
    short* dins = ws + N_HID;
    short* dE   = ws + N_HID + N_INS;
    if (i < N_HID) {
        float4 v = *(const float4*)&hid[i];
        bf4 o; o[0]=f2bf(v.x); o[1]=f2bf(v.y); o[2]=f2bf(v.z); o[3]=f2bf(v.w);
        *(bf4*)&dhid[i] = o;
    } else if (i < N_HID + N_INS) {
        int j = i - N_HID;
        float4 v = *(const float4*)&ins[j];
        bf4 o; o[0]=f2bf(v.x); o[1]=f2bf(v.y); o[2]=f2bf(v.z); o[3]=f2bf(v.w);
        *(bf4*)&dins[j] = o;
    } else {
        int j = i - N_HID - N_INS;
        if (j < N_E) {
            bf4 o;
            if (j < N_E_SRC) {
                float4 v = *(const float4*)&E[j];
                o[0]=f2bf(v.x); o[1]=f2bf(v.y); o[2]=f2bf(v.z); o[3]=f2bf(v.w);
            } else {
                o[0]=0; o[1]=0; o[2]=0; o[3]=0;
            }
            *(bf4*)&dE[j] = o;
        }
    }
}

// ---------------------------------------------------------------------------
// Cast + transpose W -> WT bf16 (WT[n][k] = W[k][n]); grid (16,16,3)
// ---------------------------------------------------------------------------
__global__ __launch_bounds__(256) void cast_wt(
    const float* __restrict__ Wq, const float* __restrict__ Wk,
    const float* __restrict__ Wv, short* __restrict__ dstbase)
{
    const float* W = (blockIdx.z==0) ? Wq : (blockIdx.z==1) ? Wk : Wv;
    short* dst = dstbase + (size_t)blockIdx.z * N_W;
    const int k0 = blockIdx.y*64, n0 = blockIdx.x*64;
    __shared__ float st[64][65];
    const int tid = threadIdx.x;
    #pragma unroll
    for (int rep=0; rep<4; rep++) {
        int u = tid + rep*256;
        int row = u >> 4, col = (u & 15) * 4;
        float4 v = *(const float4*)&W[(size_t)(k0+row)*HIDDIM + n0 + col];
        st[row][col+0]=v.x; st[row][col+1]=v.y; st[row][col+2]=v.z; st[row][col+3]=v.w;
    }
    __syncthreads();
    #pragma unroll
    for (int rep=0; rep<4; rep++) {
        int u = tid + rep*256;
        int nrow = u >> 4, kc = (u & 15) * 4;
        bf4 o;
        #pragma unroll
        for (int j=0;j<4;j++) o[j] = f2bf(st[kc+j][nrow]);
        *(bf4*)&dst[(size_t)(n0+nrow)*HIDDIM + k0 + kc] = o;
    }
}

// ---------------------------------------------------------------------------
// Fused projection GEMM (bf16 MFMA), 128x128 tiles, BK=64, 4 waves (2x2).
// R8-exact (register prefetch spills here — R9).
// ---------------------------------------------------------------------------
__global__ __launch_bounds__(256) void proj_mfma(
    const short* __restrict__ hidb, const short* __restrict__ insb,
    const short* __restrict__ WTall,
    const float* __restrict__ bq, const float* __restrict__ bk, const float* __restrict__ bv,
    short* __restrict__ qo, short* __restrict__ ko, short* __restrict__ vTo,
    short* __restrict__ iko, short* __restrict__ ivTo)
{
    const int z = blockIdx.z;
    const int bx = blockIdx.x, by = blockIdx.y;
    if (z==1 && (bx>=16 || by>=4)) return;
    const short* X = z ? insb : hidb;
    const int T   = z ? ILEN : SEQ;
    const int tsh = z ? 7 : 10;
    const int zoff= z ? 1024 : 0;
    const int m0 = by*128, n0 = bx*128;

    __shared__ short Xs[128*72];
    __shared__ short Ws[128*72];

    const int tid=threadIdx.x, w=tid>>6, lane=tid&63, quad=lane>>4, nl=lane&15;
    const int wr = w>>1, wc = w&1;

    f4 acc[4][4];
    #pragma unroll
    for (int ti=0;ti<4;ti++)
      #pragma unroll
      for (int tj=0;tj<4;tj++) { acc[ti][tj][0]=0.f; acc[ti][tj][1]=0.f; acc[ti][tj][2]=0.f; acc[ti][tj][3]=0.f; }

    for (int k0=0; k0<HIDDIM; k0+=64) {
        __syncthreads();
        #pragma unroll
        for (int rep=0; rep<4; rep++) {
            int u = tid + rep*256;
            int row = u >> 3, ch = u & 7;
            *(uint4*)&Xs[row*72 + ch*8] = *(const uint4*)&X[(size_t)(m0+row)*HIDDIM + k0 + ch*8];
            *(uint4*)&Ws[row*72 + ch*8] = *(const uint4*)&WTall[(size_t)(zoff+n0+row)*HIDDIM + k0 + ch*8];
        }
        __syncthreads();
        bf8 a[4][2], b[4][2];
        #pragma unroll
        for (int ti=0;ti<4;ti++)
          #pragma unroll
          for (int s=0;s<2;s++)
            a[ti][s] = *(const bf8*)&Xs[(64*wr + 16*ti + nl)*72 + s*32 + quad*8];
        #pragma unroll
        for (int tj=0;tj<4;tj++)
          #pragma unroll
          for (int s=0;s<2;s++)
            b[tj][s] = *(const bf8*)&Ws[(64*wc + 16*tj + nl)*72 + s*32 + quad*8];
        #pragma unroll
        for (int ti=0;ti<4;ti++)
          #pragma unroll
          for (int tj=0;tj<4;tj++)
            #pragma unroll
            for (int s=0;s<2;s++)
              acc[ti][tj] = MFMA(a[ti][s], b[tj][s], acc[ti][tj]);
    }

    #pragma unroll
    for (int tj=0;tj<4;tj++) {
        const int n = n0 + 64*wc + 16*tj + nl;
        const int nn = n & 1023;
        const int h = nn >> 6, d = nn & 63;
        float bias; short* outp; int mode;
        if (z==0) {
            if (n < 1024)      { bias = bq[nn]; outp = qo;  mode=0; }
            else if (n < 2048) { bias = bk[nn]; outp = ko;  mode=0; }
            else               { bias = bv[nn]; outp = vTo; mode=1; }
        } else {
            if (n < 1024)      { bias = bk[nn]; outp = iko;  mode=0; }
            else               { bias = bv[nn]; outp = ivTo; mode=1; }
        }
        #pragma unroll
        for (int ti=0;ti<4;ti++) {
            const int mb = m0 + 64*wr + 16*ti + quad*4;
            const int bb = mb >> tsh, tt = mb & (T-1);
            if (mode) {
                bf4 o;
                #pragma unroll
                for (int i=0;i<4;i++) o[i] = f2bf(acc[ti][tj][i] + bias);
                *(bf4*)&outp[((size_t)(bb*NH + h)*SD + d)*T + tt] = o;
            } else {
                #pragma unroll
                for (int i=0;i<4;i++)
                    outp[((size_t)(bb*NH + h)*T + tt + i)*SD + d] = f2bf(acc[ti][tj][i] + bias);
            }
        }
    }
}

// ---------------------------------------------------------------------------
// Fused attention (bf16 MFMA). BM=128 q-rows per block, 512 threads (8 waves,
// wave g owns q-rows 16g..16g+15). K/V tile 64 -> staging amortized 2x.
// Grid 8x16x4 = 512 blocks = exactly 2/CU (no tail), 16 waves/CU.
// E window 192 rows, circular mod-256 LDS. Ke band: 36 tiles split 5/4
// between the two waves sharing each k-group. Qe via in-wave shfl (exact).
// Static-shift softmax. ps aliases keT (barrier B4 between gather & store).
// LDS = 26112 + 9216 + 9216 + 36864 = 81408 B -> 2 blocks/CU.
// ---------------------------------------------------------------------------
__global__ __launch_bounds__(512,4) void attn_mfma(
    const short* __restrict__ qg, const short* __restrict__ kg, const short* __restrict__ vTg,
    const short* __restrict__ ikg, const short* __restrict__ ivTg,
    const float* __restrict__ mask, const float* __restrict__ imask,
    const float* __restrict__ gate, const short* __restrict__ Ebf,
    float* __restrict__ out)
{
    const int l0 = blockIdx.x * 128, h = blockIdx.y, b = blockIdx.z;
    const int tid = threadIdx.x, w = tid>>6, lane = tid&63, quad = lane>>4, nl = lane&15;
    const int kt = w & 3, half = w >> 2;
    const int srow = tid >> 3, sch = (tid & 7) * 8;   // staging: 512 thr = 64 rows x 8 chunks

    __shared__ short keT[192*68];     // 26112 B  keT[c][rk]=Ke[rk][c]; ps aliases
    __shared__ short ksh[64*72];      //  9216 B
    __shared__ short vts[64*72];      //  9216 B
    __shared__ short es [256*72];     // 36864 B circular (slot = row & 255); psi aliases
    short* ps  = keT;                 // P[128][72] bf16 (18432 B <= 26112)
    short* psi = es;                  // instruct P (es dead there)

    const size_t bh = (size_t)(b*NH + h);
    const short* kbase   = kg   + bh*SEQ*SD;
    const short* vTbase  = vTg  + bh*SD*SEQ;
    const short* ikbase  = ikg  + bh*ILEN*SD;
    const short* ivTbase = ivTg + bh*SD*ILEN;

    // Q A-fragments: loop-invariant, registers only (wave w: q rows 16w+nl)
    bf8 aq[2];
    {
        const short* qrow = qg + (bh*SEQ + l0 + 16*w + nl)*SD;
        #pragma unroll
        for (int s=0;s<2;s++) aq[s] = *(const bf8*)&qrow[s*32 + quad*8];
    }

    f4 o1[4], o2[4];
    float l1[4], l2[4];
    #pragma unroll
    for (int t=0;t<4;t++) {
        o1[t][0]=0.f;o1[t][1]=0.f;o1[t][2]=0.f;o1[t][3]=0.f;
        o2[t][0]=0.f;o2[t][1]=0.f;o2[t][2]=0.f;o2[t][3]=0.f;
        l1[t]=0.f; l2[t]=0.f;
    }

    // Qe in-wave gather constants (same algebra as R7-R10, wave-count agnostic)
    int srci[4]; bool ci[4];
    #pragma unroll
    for (int i=0;i<4;i++) {
        const int d0 = 4*quad + i - nl;
        srci[i] = (lane & 48) | ((d0 - 1) & 15);
        ci[i]   = (d0 >= 1);
    }

    // Ke tile assignment: wave w covers k-group kt, c-tiles ct0..ct0+nj-1
    const int nj  = half ? 4 : 5;
    const int ct0 = (half ? 8 : 3) - kt;

    // ======================= main attention over S keys =====================
    for (int r0=0; r0<SEQ; r0+=64) {
        const int jb = l0 - r0 + 960;   // E window base (192 rows, slides -64)
        __syncthreads();   // B1: prev iter's LDS reads done
        *(uint4*)&ksh[srow*72 + sch] = *(const uint4*)&kbase[(size_t)(r0+srow)*SD + sch];
        *(uint4*)&vts[srow*72 + sch] = *(const uint4*)&vTbase[(size_t)srow*SEQ + r0 + sch];
        if (r0 == 0) {     // warm-up: stage all 192 window rows
            #pragma unroll
            for (int p=0; p<3; p++) {
                const int g = jb + 64*p + srow;
                *(uint4*)&es[(g & 255)*72 + sch] = *(const uint4*)&Ebf[(size_t)g*SD + sch];
            }
        } else {           // steady: 64 new bottom rows
            const int g = jb + srow;
            *(uint4*)&es[(g & 255)*72 + sch] = *(const uint4*)&Ebf[(size_t)g*SD + sch];
        }
        __syncthreads();   // B2: staging visible

        float mk[4];
        #pragma unroll
        for (int t=0;t<4;t++) mk[t] = mask[b*SEQ + r0 + 16*t + nl] - SHIFT;

        // ---- Ke band first (short live range): A = own k-group rows ----
        bf8 ak[2];
        #pragma unroll
        for (int s=0;s<2;s++) ak[s] = *(const bf8*)&ksh[(16*kt+nl)*72 + s*32 + quad*8];
        {
            f4 ke[5];
            #pragma unroll
            for (int j=0;j<5;j++) { ke[j][0]=0.f;ke[j][1]=0.f;ke[j][2]=0.f;ke[j][3]=0.f; }
            #pragma unroll
            for (int j=0;j<5;j++) {
                if (j < nj) {
                    const int slot = (jb + 16*(ct0+j) + nl) & 255;
                    #pragma unroll
                    for (int s=0;s<2;s++) {
                        bf8 bek = *(const bf8*)&es[slot*72 + s*32 + quad*8];
                        ke[j] = MFMA(ak[s], bek, ke[j]);
                    }
                }
            }
            const int rb = 16*kt + 4*quad;
            #pragma unroll
            for (int j=0;j<5;j++) {
                if (j < nj) {
                    const int c = 16*(ct0+j) + nl;
                    bf4 pk;
                    #pragma unroll
                    for (int i=0;i<4;i++) pk[i] = f2bf(ke[j][i]);
                    *(bf4*)&keT[c*68 + rb] = pk;
                }
            }
        }
        // ---- QK^T ----
        f4 sc[4];
        #pragma unroll
        for (int t=0;t<4;t++) { sc[t][0]=0.f; sc[t][1]=0.f; sc[t][2]=0.f; sc[t][3]=0.f; }
        #pragma unroll
        for (int t=0;t<4;t++)
            #pragma unroll
            for (int s=0;s<2;s++) {
                bf8 bk = *(const bf8*)&ksh[(16*t+nl)*72 + s*32 + quad*8];
                sc[t] = MFMA(aq[s], bk, sc[t]);
            }
        // ---- Qe band: tiles w..w+4 ----
        f4 qe[5];
        #pragma unroll
        for (int j=0;j<5;j++) { qe[j][0]=0.f;qe[j][1]=0.f;qe[j][2]=0.f;qe[j][3]=0.f; }
        #pragma unroll
        for (int j=0;j<5;j++) {
            const int slot = (jb + 16*(w+j) + nl) & 255;
            #pragma unroll
            for (int s=0;s<2;s++) {
                bf8 beq = *(const bf8*)&es[slot*72 + s*32 + quad*8];
                qe[j] = MFMA(aq[s], beq, qe[j]);
            }
        }
        __syncthreads();   // B3: keT writes visible

        // ---- softmax: Qe via shfl, Ke via keT; p = exp(s - SHIFT) ----
        short pbf[4][4];
        #pragma unroll
        for (int i=0;i<4;i++) {
            const int li = 16*w + 4*quad + i;
            #pragma unroll
            for (int t=0;t<4;t++) {
                float v = ci[i] ? qe[4-t][i] : qe[3-t][i];
                const float qadd = __shfl(v, srci[i]);
                const int ri = 16*t + nl;
                const float kadd = bf2f(keT[(li - ri + 63)*68 + ri]);
                const float sval = (sc[t][i] + qadd + kadd)*0.125f + mk[t];
                const float p = __expf(sval);
                pbf[i][t] = f2bf(p);
                l1[i] += p;
            }
        }
        __syncthreads();   // B4: keT gather done everywhere; ps may overwrite

        #pragma unroll
        for (int i=0;i<4;i++) {
            const int li = 16*w + quad*4 + i;
            #pragma unroll
            for (int t=0;t<4;t++) ps[li*72 + 16*t + nl] = pbf[i][t];
        }
        // ---- PV ----
        #pragma unroll
        for (int s=0;s<2;s++) {
            bf8 ap = *(const bf8*)&ps[(16*w+nl)*72 + s*32 + quad*8];
            #pragma unroll
            for (int t=0;t<4;t++) {
                bf8 bv = *(const bf8*)&vts[(16*t+nl)*72 + s*32 + quad*8];
                o1[t] = MFMA(ap, bv, o1[t]);
            }
        }
    }

    // ==================== instruct attention over L keys ====================
    for (int r0=0; r0<ILEN; r0+=64) {
        __syncthreads();
        *(uint4*)&ksh[srow*72 + sch] = *(const uint4*)&ikbase[(size_t)(r0+srow)*SD + sch];
        *(uint4*)&vts[srow*72 + sch] = *(const uint4*)&ivTbase[(size_t)srow*ILEN + r0 + sch];
        __syncthreads();

        float im[4];
        #pragma unroll
        for (int t=0;t<4;t++) im[t] = imask[b*ILEN + r0 + 16*t + nl] - SHIFT;

        f4 sc[4];
        #pragma unroll
        for (int t=0;t<4;t++) { sc[t][0]=0.f; sc[t][1]=0.f; sc[t][2]=0.f; sc[t][3]=0.f; }
        #pragma unroll
        for (int t=0;t<4;t++)
            #pragma unroll
            for (int s=0;s<2;s++) {
                bf8 bk = *(const bf8*)&ksh[(16*t+nl)*72 + s*32 + quad*8];
                sc[t] = MFMA(aq[s], bk, sc[t]);
            }
        short pbf[4][4];
        #pragma unroll
        for (int t=0;t<4;t++) {
            #pragma unroll
            for (int i=0;i<4;i++) {
                const float p = __expf(sc[t][i]*0.125f + im[t]);
                pbf[i][t] = f2bf(p);
                l2[i] += p;
            }
        }
        // psi (alias es, dead here): wave-local rows, no barrier needed
        #pragma unroll
        for (int i=0;i<4;i++) {
            const int li = 16*w + quad*4 + i;
            #pragma unroll
            for (int t=0;t<4;t++) psi[li*72 + 16*t + nl] = pbf[i][t];
        }
        #pragma unroll
        for (int s=0;s<2;s++) {
            bf8 ap = *(const bf8*)&psi[(16*w+nl)*72 + s*32 + quad*8];
            #pragma unroll
            for (int t=0;t<4;t++) {
                bf8 bv = *(const bf8*)&vts[(16*t+nl)*72 + s*32 + quad*8];
                o2[t] = MFMA(ap, bv, o2[t]);
            }
        }
    }

    // ====================== final row-sum reductions ========================
    #pragma unroll
    for (int i=0;i<4;i++) {
        #pragma unroll
        for (int off=1; off<16; off<<=1) {
            l1[i] += __shfl_xor(l1[i], off);
            l2[i] += __shfl_xor(l2[i], off);
        }
    }

    // ============================== epilogue ================================
    const float tg = tanhf(gate[h]);
    #pragma unroll
    for (int i=0;i<4;i++) {
        const int l = l0 + 16*w + quad*4 + i;
        const float inv1 = 1.0f/l1[i], inv2 = 1.0f/l2[i];
        #pragma unroll
        for (int t=0;t<4;t++) {
            const int d = 16*t + nl;
            out[((size_t)(b*SEQ + l)*NH + h)*SD + d] = o1[t][i]*inv1 + tg*(o2[t][i]*inv2);
        }
    }
}

extern "C" void kernel_launch(void* const* d_in, const int* in_sizes, int n_in,
                              void* d_out, int out_size, void* d_ws, size_t ws_size,
                              hipStream_t stream) {
    const float* hidden  = (const float*)d_in[0];
    const float* mask    = (const float*)d_in[1];
    const float* ihidden = (const float*)d_in[2];
    const float* imask   = (const float*)d_in[3];
    const float* Wq   = (const float*)d_in[4];
    const float* bq   = (const float*)d_in[5];
    const float* Wk   = (const float*)d_in[6];
    const float* bk   = (const float*)d_in[7];
    const float* Wv   = (const float*)d_in[8];
    const float* bv   = (const float*)d_in[9];
    const float* gate = (const float*)d_in[10];
    const float* dist = (const float*)d_in[11];
    float* out = (float*)d_out;

    short* ws = (short*)d_ws;
    const size_t OFF_INS = N_HID;
    const size_t OFF_E   = OFF_INS + N_INS;
    const size_t OFF_WT  = OFF_E + N_E;
    const size_t OFF_Q   = OFF_WT + 3*(size_t)N_W;
    const size_t OFF_K   = OFF_Q + N_HID;
    const size_t OFF_VT  = OFF_K + N_HID;
    const size_t OFF_IK  = OFF_VT + N_HID;
    const size_t OFF_IVT = OFF_IK + N_INS;

    cast_flat<<<4736, 256, 0, stream>>>(hidden, ihidden, dist, ws);
    cast_wt<<<dim3(16,16,3), 256, 0, stream>>>(Wq, Wk, Wv, ws + OFF_WT);
    proj_mfma<<<dim3(24,32,2), 256, 0, stream>>>(
        ws, ws + OFF_INS, ws + OFF_WT,
        bq, bk, bv,
        ws + OFF_Q, ws + OFF_K, ws + OFF_VT, ws + OFF_IK, ws + OFF_IVT);
    attn_mfma<<<dim3(8,16,4), 512, 0, stream>>>(
        ws + OFF_Q, ws + OFF_K, ws + OFF_VT, ws + OFF_IK, ws + OFF_IVT,
        mask, imask, gate, ws + OFF_E, out);
}